// Round 13
// baseline (155.861 us; speedup 1.0000x reference)
//
#include <hip/hip_runtime.h>

#define LEAKY_SLOPE 0.2f
#define SHIFT 20.0f     // uniform softmax shift: ratio-invariant, keeps exp() in fp32 range
#define CHUNK 64        // nodes per accum block -> 1564 blocks (~6/CU), 1 iter/thread
#define LG_CHUNK 6
#define NB_MAX 2048     // LDS counter arrays: 2*8 KB
#define EPB 2048        // edges per scatter block (8/thread) -> 782 blocks (~3/CU)

// ---------------------------------------------------------------------------
// R12 (133.7 us): per-src-chunk buckets + direct LDS finalize works; accum
// FETCH 36.5 MB == buckets 6.4 + sv 3.2x8 XCDs (per-XCD L2-resident) + su/ht;
// WRITE 0.39 MB. Both kernels are ~2x their traffic roofline -> latency-bound
// at low blocks/CU. R13: double TLP in both (CHUNK 128->64, EPB 4096->2048).
//
// ws: [su: n*8 f32][sv: n*8 f32][gcur: nb u32][buckets: nb*cap u32]
// fallback (small ws / n >= 2^17): R5 device-atomic path
// ---------------------------------------------------------------------------

__device__ __forceinline__ float lrelu_exp(float a, float b) {
    float e = a + b;
    e = (e > 0.f) ? e : LEAKY_SLOPE * e;
    return __expf(e - SHIFT);
}

// ---------------- fused table + scatter (disjoint block ranges) -------------
// blocks [0, gs): scatter edges into packed per-chunk buckets
// blocks [gs, gs+gu): compute su / sv tables
__global__ __launch_bounds__(256) void table_scatter_kernel(
        const float* __restrict__ x, const float* __restrict__ a,
        const int* __restrict__ src, const int* __restrict__ dst,
        const int* __restrict__ typ,
        float* __restrict__ su, float* __restrict__ sv,
        unsigned* __restrict__ gcur, unsigned* __restrict__ buckets,
        int cap, int nb, int n_units, int n_edges, int gs) {
    const int tid = threadIdx.x;

    if ((int)blockIdx.x < gs) {
        // ------------------ scatter ------------------
        __shared__ unsigned lcnt[NB_MAX];
        __shared__ unsigned lbase[NB_MAX];
        for (int i = tid; i < nb; i += 256) lcnt[i] = 0u;
        __syncthreads();

        const int base = blockIdx.x * EPB;
        unsigned ent[8], rnk[8], bkt[8];
#pragma unroll
        for (int r = 0; r < 2; ++r) {
            int e = base + tid * 4 + r * 1024;
            if (e + 4 <= n_edges) {
                int4 s4 = *reinterpret_cast<const int4*>(src + e);
                int4 d4 = *reinterpret_cast<const int4*>(dst + e);
                int4 t4 = *reinterpret_cast<const int4*>(typ + e);
                int ss[4] = {s4.x, s4.y, s4.z, s4.w};
                int dd[4] = {d4.x, d4.y, d4.z, d4.w};
                int tt[4] = {t4.x, t4.y, t4.z, t4.w};
#pragma unroll
                for (int i = 0; i < 4; ++i) {
                    unsigned s = (unsigned)ss[i], d = (unsigned)dd[i], t = (unsigned)tt[i];
                    unsigned b = s >> LG_CHUNK;
                    ent[r * 4 + i] = ((s & (CHUNK - 1)) << 21) | (t << 18) | d;
                    bkt[r * 4 + i] = b;
                    rnk[r * 4 + i] = atomicAdd(&lcnt[b], 1u);
                }
            } else {
#pragma unroll
                for (int i = 0; i < 4; ++i) {
                    int ee = e + i;
                    if (ee < n_edges) {
                        unsigned s = (unsigned)src[ee], d = (unsigned)dst[ee],
                                 t = (unsigned)typ[ee];
                        unsigned b = s >> LG_CHUNK;
                        ent[r * 4 + i] = ((s & (CHUNK - 1)) << 21) | (t << 18) | d;
                        bkt[r * 4 + i] = b;
                        rnk[r * 4 + i] = atomicAdd(&lcnt[b], 1u);
                    } else {
                        bkt[r * 4 + i] = 0xFFFFFFFFu;
                    }
                }
            }
        }
        __syncthreads();
        for (int i = tid; i < nb; i += 256)
            lbase[i] = lcnt[i] ? atomicAdd(&gcur[i], lcnt[i]) : 0u;
        __syncthreads();
#pragma unroll
        for (int k = 0; k < 8; ++k) {
            unsigned b = bkt[k];
            if (b != 0xFFFFFFFFu) {
                unsigned pos = lbase[b] + rnk[k];
                if (pos < (unsigned)cap)      // 8-sigma margin; effectively never
                    buckets[(size_t)b * cap + pos] = ent[k];
            }
        }
    } else {
        // ------------------ node tables ------------------
        int u = ((int)blockIdx.x - gs) * 256 + tid;
        if (u >= n_units) return;
        float4 xr[16];
        const float4* xp = reinterpret_cast<const float4*>(x + (size_t)u * 64);
#pragma unroll
        for (int k = 0; k < 16; ++k) xr[k] = xp[k];

        float out_u[8], out_v[8];
#pragma unroll
        for (int r = 0; r < 8; ++r) {
            const float* ar = a + r * 128;    // wave-uniform -> scalar loads
            float au = 0.f, av = 0.f;
#pragma unroll
            for (int k = 0; k < 16; ++k) {
                float4 xk = xr[k];
                au = fmaf(ar[4 * k + 0], xk.x, au);
                au = fmaf(ar[4 * k + 1], xk.y, au);
                au = fmaf(ar[4 * k + 2], xk.z, au);
                au = fmaf(ar[4 * k + 3], xk.w, au);
                av = fmaf(ar[64 + 4 * k + 0], xk.x, av);
                av = fmaf(ar[64 + 4 * k + 1], xk.y, av);
                av = fmaf(ar[64 + 4 * k + 2], xk.z, av);
                av = fmaf(ar[64 + 4 * k + 3], xk.w, av);
            }
            out_u[r] = au;
            out_v[r] = av;
        }
        float4* sup = reinterpret_cast<float4*>(su + (size_t)u * 8);
        sup[0] = make_float4(out_u[0], out_u[1], out_u[2], out_u[3]);
        sup[1] = make_float4(out_u[4], out_u[5], out_u[6], out_u[7]);
        float4* svp = reinterpret_cast<float4*>(sv + (size_t)u * 8);
        svp[0] = make_float4(out_v[0], out_v[1], out_v[2], out_v[3]);
        svp[1] = make_float4(out_v[4], out_v[5], out_v[6], out_v[7]);
    }
}

// ---------------- accumulate chunk c + finalize (no partials) ---------------
__device__ __forceinline__ void accum_edge(unsigned e, const float* __restrict__ suc,
                                           const float* __restrict__ sv,
                                           const float* __restrict__ hat_t,
                                           float* __restrict__ lden,
                                           float* __restrict__ lnum) {
    unsigned s_l = e >> 21;
    unsigned t = (e >> 18) & 7u;
    unsigned d = e & 0x3FFFFu;
    float suv = suc[(s_l << 3) | t];
    float svv = sv[((size_t)d << 3) | t];
    float ht = hat_t[d];
    float ex = lrelu_exp(suv, svv);
    atomicAdd(&lden[s_l], ex);            // ds_add_f32
    atomicAdd(&lnum[s_l], ex * ht);
}

__global__ __launch_bounds__(256) void accum_final_kernel(
        const unsigned* __restrict__ buckets, const unsigned* __restrict__ gcur,
        const float* __restrict__ su, const float* __restrict__ sv,
        const float* __restrict__ hat_t, float* __restrict__ out,
        int cap, int n_units) {
    __shared__ float lden[CHUNK];
    __shared__ float lnum[CHUNK];
    const int c = blockIdx.x;
    const int tid = threadIdx.x;
    if (tid < CHUNK) { lden[tid] = 0.f; lnum[tid] = 0.f; }
    __syncthreads();

    int cnt = (int)gcur[c];
    if (cnt > cap) cnt = cap;
    const unsigned* ep = buckets + (size_t)c * cap;
    const float* suc = su + (((size_t)c << LG_CHUNK) << 3);

    for (int i = tid * 4; i + 4 <= cnt; i += 1024) {
        uint4 q = *reinterpret_cast<const uint4*>(ep + i);
        accum_edge(q.x, suc, sv, hat_t, lden, lnum);
        accum_edge(q.y, suc, sv, hat_t, lden, lnum);
        accum_edge(q.z, suc, sv, hat_t, lden, lnum);
        accum_edge(q.w, suc, sv, hat_t, lden, lnum);
    }
    int rem = cnt & 3;                    // leftover quad tail
    if (tid < rem) accum_edge(ep[cnt - rem + tid], suc, sv, hat_t, lden, lnum);

    __syncthreads();
    int u = (c << LG_CHUNK) + tid;
    if (tid < CHUNK && u < n_units) {
        float den = lden[tid];
        out[u] = (den > 0.f) ? lnum[tid] / den : 0.f;   // empty segment -> 0
    }
}

// ------------------------- fallback (small ws): R5 path ---------------------
template <bool FUSED>
__global__ __launch_bounds__(256) void node_table_fb_kernel(const float* __restrict__ x,
                                                            const float* __restrict__ a,
                                                            const float* __restrict__ hat_t,
                                                            float* __restrict__ su,
                                                            float* __restrict__ svx,
                                                            float2* __restrict__ nd,
                                                            int n_units) {
    int u = blockIdx.x * blockDim.x + threadIdx.x;
    if (u >= n_units) return;
    nd[u] = make_float2(0.f, 0.f);
    float4 xr[16];
    const float4* xp = reinterpret_cast<const float4*>(x + (size_t)u * 64);
#pragma unroll
    for (int k = 0; k < 16; ++k) xr[k] = xp[k];
    float out_u[8], out_v[8];
#pragma unroll
    for (int r = 0; r < 8; ++r) {
        const float* ar = a + r * 128;
        float au = 0.f, av = 0.f;
#pragma unroll
        for (int k = 0; k < 16; ++k) {
            float4 xk = xr[k];
            au = fmaf(ar[4 * k + 0], xk.x, au);
            au = fmaf(ar[4 * k + 1], xk.y, au);
            au = fmaf(ar[4 * k + 2], xk.z, au);
            au = fmaf(ar[4 * k + 3], xk.w, au);
            av = fmaf(ar[64 + 4 * k + 0], xk.x, av);
            av = fmaf(ar[64 + 4 * k + 1], xk.y, av);
            av = fmaf(ar[64 + 4 * k + 2], xk.z, av);
            av = fmaf(ar[64 + 4 * k + 3], xk.w, av);
        }
        out_u[r] = au;
        out_v[r] = av;
    }
    float4* sup = reinterpret_cast<float4*>(su + (size_t)u * 8);
    sup[0] = make_float4(out_u[0], out_u[1], out_u[2], out_u[3]);
    sup[1] = make_float4(out_u[4], out_u[5], out_u[6], out_u[7]);
    if (FUSED) {
        float ht = hat_t[u];
        float4* svp = reinterpret_cast<float4*>(svx + (size_t)u * 16);
        svp[0] = make_float4(out_v[0], ht, out_v[1], ht);
        svp[1] = make_float4(out_v[2], ht, out_v[3], ht);
        svp[2] = make_float4(out_v[4], ht, out_v[5], ht);
        svp[3] = make_float4(out_v[6], ht, out_v[7], ht);
    } else {
        float4* svp = reinterpret_cast<float4*>(svx + (size_t)u * 8);
        svp[0] = make_float4(out_v[0], out_v[1], out_v[2], out_v[3]);
        svp[1] = make_float4(out_v[4], out_v[5], out_v[6], out_v[7]);
    }
}

__device__ __forceinline__ void pair_add_dev(float* f, float a, float b) {
    atomicAdd(f, a);
    atomicAdd(f + 1, b);
}

template <bool FUSED>
__global__ __launch_bounds__(256) void edge_sum_kernel(const int* __restrict__ src,
                                                       const int* __restrict__ dst,
                                                       const int* __restrict__ typ,
                                                       const float* __restrict__ su,
                                                       const float* __restrict__ svx,
                                                       const float* __restrict__ hat_t,
                                                       float2* __restrict__ nd,
                                                       int n_edges) {
    int e0 = (blockIdx.x * blockDim.x + threadIdx.x) * 2;
    float* ndf = (float*)nd;
    if (e0 + 1 < n_edges) {
        int2 s2 = *reinterpret_cast<const int2*>(src + e0);
        int2 d2 = *reinterpret_cast<const int2*>(dst + e0);
        int2 t2 = *reinterpret_cast<const int2*>(typ + e0);
        float su0 = su[(size_t)s2.x * 8 + t2.x];
        float su1 = su[(size_t)s2.y * 8 + t2.y];
        float sv0, sv1, ht0, ht1;
        if (FUSED) {
            const float2* svh = reinterpret_cast<const float2*>(svx);
            float2 p0 = svh[(size_t)d2.x * 8 + t2.x];
            float2 p1 = svh[(size_t)d2.y * 8 + t2.y];
            sv0 = p0.x; ht0 = p0.y;
            sv1 = p1.x; ht1 = p1.y;
        } else {
            sv0 = svx[(size_t)d2.x * 8 + t2.x];
            sv1 = svx[(size_t)d2.y * 8 + t2.y];
            ht0 = hat_t[d2.x];
            ht1 = hat_t[d2.y];
        }
        float ex0 = lrelu_exp(su0, sv0);
        float ex1 = lrelu_exp(su1, sv1);
        pair_add_dev(ndf + 2 * (size_t)s2.x, ex0, ex0 * ht0);
        pair_add_dev(ndf + 2 * (size_t)s2.y, ex1, ex1 * ht1);
    } else if (e0 < n_edges) {
        int s = src[e0], d = dst[e0], t = typ[e0];
        float sv_v, ht;
        if (FUSED) {
            float2 p = reinterpret_cast<const float2*>(svx)[(size_t)d * 8 + t];
            sv_v = p.x; ht = p.y;
        } else {
            sv_v = svx[(size_t)d * 8 + t];
            ht = hat_t[d];
        }
        float ex = lrelu_exp(su[(size_t)s * 8 + t], sv_v);
        pair_add_dev(ndf + 2 * (size_t)s, ex, ex * ht);
    }
}

__global__ __launch_bounds__(256) void finalize_kernel(const float2* __restrict__ nd,
                                                       float* __restrict__ out, int n) {
    int i = blockIdx.x * blockDim.x + threadIdx.x;
    if (i < n) {
        float2 v = nd[i];
        out[i] = (v.x > 0.f) ? v.y / v.x : 0.f;
    }
}

extern "C" void kernel_launch(void* const* d_in, const int* in_sizes, int n_in,
                              void* d_out, int out_size, void* d_ws, size_t ws_size,
                              hipStream_t stream) {
    const float* x     = (const float*)d_in[0];   // (n_units, 64)
    const float* hat_t = (const float*)d_in[1];   // (n_units,)
    const float* a     = (const float*)d_in[2];   // (8, 128)
    const int*   ei    = (const int*)d_in[3];     // (2, n_edges)
    const int*   et    = (const int*)d_in[4];     // (n_edges,)

    const int n_units = in_sizes[1];
    const int n_edges = in_sizes[4];
    const int* src = ei;
    const int* dst = ei + n_edges;

    const size_t n = (size_t)n_units;
    const int B = 256;
    const int gu = (n_units + B - 1) / B;
    char* ws = (char*)d_ws;

    const int nb = (n_units + CHUNK - 1) >> LG_CHUNK;   // = #chunks = #accum blocks
    const size_t tab = n * 64;                          // su 32 B + sv 32 B per node
    const size_t curb = ((size_t)nb * 4 + 255) & ~255;

    // bucket capacity: mean + 8 sigma (binomial), rounded up to quad
    int cap = 0;
    if (nb <= NB_MAX && n_units < (1 << 17)) {
        double mean = (double)n_edges / nb;
        int cap_min = ((int)(mean + 8.0 * __builtin_sqrt(mean) + 16.0) + 3) & ~3;
        size_t head = tab + curb;
        if (ws_size > head) {
            int cmax = (int)((ws_size - head) / ((size_t)nb * 4)) & ~3;
            if (cmax >= cap_min) cap = cap_min;
        }
    }

    if (cap > 0) {
        // ---- per-chunk bucket path: 3 dispatches, no partials/reduce ----
        float* su        = (float*)ws;
        float* sv        = su + n * 8;
        unsigned* gcur   = (unsigned*)(ws + tab);
        unsigned* buckets = (unsigned*)(ws + tab + curb);
        const int gs = (n_edges + EPB - 1) / EPB;

        hipMemsetAsync(gcur, 0, (size_t)nb * 4, stream);
        table_scatter_kernel<<<gs + gu, B, 0, stream>>>(x, a, src, dst, et,
                                                        su, sv, gcur, buckets,
                                                        cap, nb, n_units, n_edges, gs);
        accum_final_kernel<<<nb, B, 0, stream>>>(buckets, gcur, su, sv, hat_t,
                                                 (float*)d_out, cap, n_units);
    } else if (ws_size >= n * 104) {
        // ---- fallback: fused tables + device atomics (R5, ~265 us) ----
        float2* nd = (float2*)ws;
        float* su  = (float*)(ws + n * 8);
        float* svx = su + n * 8;
        const int ge = ((n_edges + 1) / 2 + B - 1) / B;
        node_table_fb_kernel<true><<<gu, B, 0, stream>>>(x, a, hat_t, su, svx, nd, n_units);
        edge_sum_kernel<true><<<ge, B, 0, stream>>>(src, dst, et, su, svx, hat_t, nd, n_edges);
        finalize_kernel<<<gu, B, 0, stream>>>(nd, (float*)d_out, n_units);
    } else {
        // ---- minimal ws ----
        float2* nd = (float2*)ws;
        float* su  = (float*)(ws + n * 8);
        float* svx = su + n * 8;
        const int ge = ((n_edges + 1) / 2 + B - 1) / B;
        node_table_fb_kernel<false><<<gu, B, 0, stream>>>(x, a, hat_t, su, svx, nd, n_units);
        edge_sum_kernel<false><<<ge, B, 0, stream>>>(src, dst, et, su, svx, hat_t, nd, n_edges);
        finalize_kernel<<<gu, B, 0, stream>>>(nd, (float*)d_out, n_units);
    }
}

// Round 14
// 135.416 us; speedup vs baseline: 1.1510x; 1.1510x over previous
//
#include <hip/hip_runtime.h>

#define LEAKY_SLOPE 0.2f
#define SHIFT 20.0f     // uniform softmax shift: ratio-invariant, keeps exp() in fp32 range
#define CHUNK 128       // nodes per accum block (R12 proven; R13's 64 fragmented scatter writes)
#define LG_CHUNK 7
#define NB_MAX 1024     // scatter LDS counter array: 4 KB
#define EPB 4096        // edges per scatter block (16/thread); runs = EPB/nb ~ 5 entries

// ---------------------------------------------------------------------------
// R13 post-mortem: scatter WRITE 48 MB == 4 B stores with ~1.3-entry bucket
// runs (EPB/nb collapsed) -> reverted to R12 (CHUNK=128, EPB=4096, 133.7 us).
// R14: (1) accum loads 8 edges/thread (2 x uint4 back-to-back) -> one pass,
// 2x gather MLP, same traffic; (2) scatter reuses lcnt for base (saves 4 KB).
//
// ws: [su: n*8 f32][sv: n*8 f32][gcur: nb u32][buckets: nb*cap u32]
// fallback (small ws / n >= 2^18): R5 device-atomic path
// ---------------------------------------------------------------------------

__device__ __forceinline__ float lrelu_exp(float a, float b) {
    float e = a + b;
    e = (e > 0.f) ? e : LEAKY_SLOPE * e;
    return __expf(e - SHIFT);
}

// ---------------- fused table + scatter (disjoint block ranges) -------------
// blocks [0, gs): scatter edges into packed per-chunk buckets
// blocks [gs, gs+gu): compute su / sv tables
__global__ __launch_bounds__(256) void table_scatter_kernel(
        const float* __restrict__ x, const float* __restrict__ a,
        const int* __restrict__ src, const int* __restrict__ dst,
        const int* __restrict__ typ,
        float* __restrict__ su, float* __restrict__ sv,
        unsigned* __restrict__ gcur, unsigned* __restrict__ buckets,
        int cap, int nb, int n_units, int n_edges, int gs) {
    const int tid = threadIdx.x;

    if ((int)blockIdx.x < gs) {
        // ------------------ scatter ------------------
        __shared__ unsigned lcnt[NB_MAX];   // phase 1: counts; phase 2: global bases
        for (int i = tid; i < nb; i += 256) lcnt[i] = 0u;
        __syncthreads();

        const int base = blockIdx.x * EPB;
        unsigned ent[16], rnk[16], bkt[16];
#pragma unroll
        for (int r = 0; r < 4; ++r) {
            int e = base + tid * 4 + r * 1024;
            if (e + 4 <= n_edges) {
                int4 s4 = *reinterpret_cast<const int4*>(src + e);
                int4 d4 = *reinterpret_cast<const int4*>(dst + e);
                int4 t4 = *reinterpret_cast<const int4*>(typ + e);
                int ss[4] = {s4.x, s4.y, s4.z, s4.w};
                int dd[4] = {d4.x, d4.y, d4.z, d4.w};
                int tt[4] = {t4.x, t4.y, t4.z, t4.w};
#pragma unroll
                for (int i = 0; i < 4; ++i) {
                    unsigned s = (unsigned)ss[i], d = (unsigned)dd[i], t = (unsigned)tt[i];
                    unsigned b = s >> LG_CHUNK;
                    ent[r * 4 + i] = ((s & (CHUNK - 1)) << 21) | (t << 18) | d;
                    bkt[r * 4 + i] = b;
                    rnk[r * 4 + i] = atomicAdd(&lcnt[b], 1u);
                }
            } else {
#pragma unroll
                for (int i = 0; i < 4; ++i) {
                    int ee = e + i;
                    if (ee < n_edges) {
                        unsigned s = (unsigned)src[ee], d = (unsigned)dst[ee],
                                 t = (unsigned)typ[ee];
                        unsigned b = s >> LG_CHUNK;
                        ent[r * 4 + i] = ((s & (CHUNK - 1)) << 21) | (t << 18) | d;
                        bkt[r * 4 + i] = b;
                        rnk[r * 4 + i] = atomicAdd(&lcnt[b], 1u);
                    } else {
                        bkt[r * 4 + i] = 0xFFFFFFFFu;
                    }
                }
            }
        }
        __syncthreads();
        // reserve global ranges; overwrite lcnt with the base (same owner thread)
        for (int i = tid; i < nb; i += 256) {
            unsigned c = lcnt[i];
            lcnt[i] = c ? atomicAdd(&gcur[i], c) : 0u;
        }
        __syncthreads();
#pragma unroll
        for (int k = 0; k < 16; ++k) {
            unsigned b = bkt[k];
            if (b != 0xFFFFFFFFu) {
                unsigned pos = lcnt[b] + rnk[k];
                if (pos < (unsigned)cap)      // 8-sigma margin; effectively never
                    buckets[(size_t)b * cap + pos] = ent[k];
            }
        }
    } else {
        // ------------------ node tables ------------------
        int u = ((int)blockIdx.x - gs) * 256 + tid;
        if (u >= n_units) return;
        float4 xr[16];
        const float4* xp = reinterpret_cast<const float4*>(x + (size_t)u * 64);
#pragma unroll
        for (int k = 0; k < 16; ++k) xr[k] = xp[k];

        float out_u[8], out_v[8];
#pragma unroll
        for (int r = 0; r < 8; ++r) {
            const float* ar = a + r * 128;    // wave-uniform -> scalar loads
            float au = 0.f, av = 0.f;
#pragma unroll
            for (int k = 0; k < 16; ++k) {
                float4 xk = xr[k];
                au = fmaf(ar[4 * k + 0], xk.x, au);
                au = fmaf(ar[4 * k + 1], xk.y, au);
                au = fmaf(ar[4 * k + 2], xk.z, au);
                au = fmaf(ar[4 * k + 3], xk.w, au);
                av = fmaf(ar[64 + 4 * k + 0], xk.x, av);
                av = fmaf(ar[64 + 4 * k + 1], xk.y, av);
                av = fmaf(ar[64 + 4 * k + 2], xk.z, av);
                av = fmaf(ar[64 + 4 * k + 3], xk.w, av);
            }
            out_u[r] = au;
            out_v[r] = av;
        }
        float4* sup = reinterpret_cast<float4*>(su + (size_t)u * 8);
        sup[0] = make_float4(out_u[0], out_u[1], out_u[2], out_u[3]);
        sup[1] = make_float4(out_u[4], out_u[5], out_u[6], out_u[7]);
        float4* svp = reinterpret_cast<float4*>(sv + (size_t)u * 8);
        svp[0] = make_float4(out_v[0], out_v[1], out_v[2], out_v[3]);
        svp[1] = make_float4(out_v[4], out_v[5], out_v[6], out_v[7]);
    }
}

// ---------------- accumulate chunk c + finalize (no partials) ---------------
__device__ __forceinline__ void accum_edge(unsigned e, const float* __restrict__ suc,
                                           const float* __restrict__ sv,
                                           const float* __restrict__ hat_t,
                                           float* __restrict__ lden,
                                           float* __restrict__ lnum) {
    unsigned s_l = e >> 21;
    unsigned t = (e >> 18) & 7u;
    unsigned d = e & 0x3FFFFu;
    float suv = suc[(s_l << 3) | t];
    float svv = sv[((size_t)d << 3) | t];
    float ht = hat_t[d];
    float ex = lrelu_exp(suv, svv);
    atomicAdd(&lden[s_l], ex);            // ds_add_f32
    atomicAdd(&lnum[s_l], ex * ht);
}

__global__ __launch_bounds__(256) void accum_final_kernel(
        const unsigned* __restrict__ buckets, const unsigned* __restrict__ gcur,
        const float* __restrict__ su, const float* __restrict__ sv,
        const float* __restrict__ hat_t, float* __restrict__ out,
        int cap, int n_units) {
    __shared__ float lden[CHUNK];
    __shared__ float lnum[CHUNK];
    const int c = blockIdx.x;
    const int tid = threadIdx.x;
    if (tid < CHUNK) { lden[tid] = 0.f; lnum[tid] = 0.f; }
    __syncthreads();

    int cnt = (int)gcur[c];
    if (cnt > cap) cnt = cap;
    const unsigned* ep = buckets + (size_t)c * cap;
    const float* suc = su + (((size_t)c << LG_CHUNK) << 3);

    // 8 edges/thread: two back-to-back uint4 loads -> 8 independent gather chains
    for (int i = tid * 8; i + 8 <= cnt; i += 2048) {
        uint4 q0 = *reinterpret_cast<const uint4*>(ep + i);
        uint4 q1 = *reinterpret_cast<const uint4*>(ep + i + 4);
        accum_edge(q0.x, suc, sv, hat_t, lden, lnum);
        accum_edge(q0.y, suc, sv, hat_t, lden, lnum);
        accum_edge(q0.z, suc, sv, hat_t, lden, lnum);
        accum_edge(q0.w, suc, sv, hat_t, lden, lnum);
        accum_edge(q1.x, suc, sv, hat_t, lden, lnum);
        accum_edge(q1.y, suc, sv, hat_t, lden, lnum);
        accum_edge(q1.z, suc, sv, hat_t, lden, lnum);
        accum_edge(q1.w, suc, sv, hat_t, lden, lnum);
    }
    int rem = cnt & 7;                    // leftover tail
    if (tid < rem) accum_edge(ep[cnt - rem + tid], suc, sv, hat_t, lden, lnum);

    __syncthreads();
    int u = (c << LG_CHUNK) + tid;
    if (tid < CHUNK && u < n_units) {
        float den = lden[tid];
        out[u] = (den > 0.f) ? lnum[tid] / den : 0.f;   // empty segment -> 0
    }
}

// ------------------------- fallback (small ws): R5 path ---------------------
template <bool FUSED>
__global__ __launch_bounds__(256) void node_table_fb_kernel(const float* __restrict__ x,
                                                            const float* __restrict__ a,
                                                            const float* __restrict__ hat_t,
                                                            float* __restrict__ su,
                                                            float* __restrict__ svx,
                                                            float2* __restrict__ nd,
                                                            int n_units) {
    int u = blockIdx.x * blockDim.x + threadIdx.x;
    if (u >= n_units) return;
    nd[u] = make_float2(0.f, 0.f);
    float4 xr[16];
    const float4* xp = reinterpret_cast<const float4*>(x + (size_t)u * 64);
#pragma unroll
    for (int k = 0; k < 16; ++k) xr[k] = xp[k];
    float out_u[8], out_v[8];
#pragma unroll
    for (int r = 0; r < 8; ++r) {
        const float* ar = a + r * 128;
        float au = 0.f, av = 0.f;
#pragma unroll
        for (int k = 0; k < 16; ++k) {
            float4 xk = xr[k];
            au = fmaf(ar[4 * k + 0], xk.x, au);
            au = fmaf(ar[4 * k + 1], xk.y, au);
            au = fmaf(ar[4 * k + 2], xk.z, au);
            au = fmaf(ar[4 * k + 3], xk.w, au);
            av = fmaf(ar[64 + 4 * k + 0], xk.x, av);
            av = fmaf(ar[64 + 4 * k + 1], xk.y, av);
            av = fmaf(ar[64 + 4 * k + 2], xk.z, av);
            av = fmaf(ar[64 + 4 * k + 3], xk.w, av);
        }
        out_u[r] = au;
        out_v[r] = av;
    }
    float4* sup = reinterpret_cast<float4*>(su + (size_t)u * 8);
    sup[0] = make_float4(out_u[0], out_u[1], out_u[2], out_u[3]);
    sup[1] = make_float4(out_u[4], out_u[5], out_u[6], out_u[7]);
    if (FUSED) {
        float ht = hat_t[u];
        float4* svp = reinterpret_cast<float4*>(svx + (size_t)u * 16);
        svp[0] = make_float4(out_v[0], ht, out_v[1], ht);
        svp[1] = make_float4(out_v[2], ht, out_v[3], ht);
        svp[2] = make_float4(out_v[4], ht, out_v[5], ht);
        svp[3] = make_float4(out_v[6], ht, out_v[7], ht);
    } else {
        float4* svp = reinterpret_cast<float4*>(svx + (size_t)u * 8);
        svp[0] = make_float4(out_v[0], out_v[1], out_v[2], out_v[3]);
        svp[1] = make_float4(out_v[4], out_v[5], out_v[6], out_v[7]);
    }
}

__device__ __forceinline__ void pair_add_dev(float* f, float a, float b) {
    atomicAdd(f, a);
    atomicAdd(f + 1, b);
}

template <bool FUSED>
__global__ __launch_bounds__(256) void edge_sum_kernel(const int* __restrict__ src,
                                                       const int* __restrict__ dst,
                                                       const int* __restrict__ typ,
                                                       const float* __restrict__ su,
                                                       const float* __restrict__ svx,
                                                       const float* __restrict__ hat_t,
                                                       float2* __restrict__ nd,
                                                       int n_edges) {
    int e0 = (blockIdx.x * blockDim.x + threadIdx.x) * 2;
    float* ndf = (float*)nd;
    if (e0 + 1 < n_edges) {
        int2 s2 = *reinterpret_cast<const int2*>(src + e0);
        int2 d2 = *reinterpret_cast<const int2*>(dst + e0);
        int2 t2 = *reinterpret_cast<const int2*>(typ + e0);
        float su0 = su[(size_t)s2.x * 8 + t2.x];
        float su1 = su[(size_t)s2.y * 8 + t2.y];
        float sv0, sv1, ht0, ht1;
        if (FUSED) {
            const float2* svh = reinterpret_cast<const float2*>(svx);
            float2 p0 = svh[(size_t)d2.x * 8 + t2.x];
            float2 p1 = svh[(size_t)d2.y * 8 + t2.y];
            sv0 = p0.x; ht0 = p0.y;
            sv1 = p1.x; ht1 = p1.y;
        } else {
            sv0 = svx[(size_t)d2.x * 8 + t2.x];
            sv1 = svx[(size_t)d2.y * 8 + t2.y];
            ht0 = hat_t[d2.x];
            ht1 = hat_t[d2.y];
        }
        float ex0 = lrelu_exp(su0, sv0);
        float ex1 = lrelu_exp(su1, sv1);
        pair_add_dev(ndf + 2 * (size_t)s2.x, ex0, ex0 * ht0);
        pair_add_dev(ndf + 2 * (size_t)s2.y, ex1, ex1 * ht1);
    } else if (e0 < n_edges) {
        int s = src[e0], d = dst[e0], t = typ[e0];
        float sv_v, ht;
        if (FUSED) {
            float2 p = reinterpret_cast<const float2*>(svx)[(size_t)d * 8 + t];
            sv_v = p.x; ht = p.y;
        } else {
            sv_v = svx[(size_t)d * 8 + t];
            ht = hat_t[d];
        }
        float ex = lrelu_exp(su[(size_t)s * 8 + t], sv_v);
        pair_add_dev(ndf + 2 * (size_t)s, ex, ex * ht);
    }
}

__global__ __launch_bounds__(256) void finalize_kernel(const float2* __restrict__ nd,
                                                       float* __restrict__ out, int n) {
    int i = blockIdx.x * blockDim.x + threadIdx.x;
    if (i < n) {
        float2 v = nd[i];
        out[i] = (v.x > 0.f) ? v.y / v.x : 0.f;
    }
}

extern "C" void kernel_launch(void* const* d_in, const int* in_sizes, int n_in,
                              void* d_out, int out_size, void* d_ws, size_t ws_size,
                              hipStream_t stream) {
    const float* x     = (const float*)d_in[0];   // (n_units, 64)
    const float* hat_t = (const float*)d_in[1];   // (n_units,)
    const float* a     = (const float*)d_in[2];   // (8, 128)
    const int*   ei    = (const int*)d_in[3];     // (2, n_edges)
    const int*   et    = (const int*)d_in[4];     // (n_edges,)

    const int n_units = in_sizes[1];
    const int n_edges = in_sizes[4];
    const int* src = ei;
    const int* dst = ei + n_edges;

    const size_t n = (size_t)n_units;
    const int B = 256;
    const int gu = (n_units + B - 1) / B;
    char* ws = (char*)d_ws;

    const int nb = (n_units + CHUNK - 1) >> LG_CHUNK;   // = #chunks = #accum blocks
    const size_t tab = n * 64;                          // su 32 B + sv 32 B per node
    const size_t curb = ((size_t)nb * 4 + 255) & ~255;

    // bucket capacity: mean + 8 sigma (binomial), rounded up to quad
    int cap = 0;
    if (nb <= NB_MAX && n_units < (1 << 18)) {
        double mean = (double)n_edges / nb;
        int cap_min = ((int)(mean + 8.0 * __builtin_sqrt(mean) + 16.0) + 3) & ~3;
        size_t head = tab + curb;
        if (ws_size > head) {
            int cmax = (int)((ws_size - head) / ((size_t)nb * 4)) & ~3;
            if (cmax >= cap_min) cap = cap_min;
        }
    }

    if (cap > 0) {
        // ---- per-chunk bucket path: 3 dispatches, no partials/reduce ----
        float* su        = (float*)ws;
        float* sv        = su + n * 8;
        unsigned* gcur   = (unsigned*)(ws + tab);
        unsigned* buckets = (unsigned*)(ws + tab + curb);
        const int gs = (n_edges + EPB - 1) / EPB;

        hipMemsetAsync(gcur, 0, (size_t)nb * 4, stream);
        table_scatter_kernel<<<gs + gu, B, 0, stream>>>(x, a, src, dst, et,
                                                        su, sv, gcur, buckets,
                                                        cap, nb, n_units, n_edges, gs);
        accum_final_kernel<<<nb, B, 0, stream>>>(buckets, gcur, su, sv, hat_t,
                                                 (float*)d_out, cap, n_units);
    } else if (ws_size >= n * 104) {
        // ---- fallback: fused tables + device atomics (R5, ~265 us) ----
        float2* nd = (float2*)ws;
        float* su  = (float*)(ws + n * 8);
        float* svx = su + n * 8;
        const int ge = ((n_edges + 1) / 2 + B - 1) / B;
        node_table_fb_kernel<true><<<gu, B, 0, stream>>>(x, a, hat_t, su, svx, nd, n_units);
        edge_sum_kernel<true><<<ge, B, 0, stream>>>(src, dst, et, su, svx, hat_t, nd, n_edges);
        finalize_kernel<<<gu, B, 0, stream>>>(nd, (float*)d_out, n_units);
    } else {
        // ---- minimal ws ----
        float2* nd = (float2*)ws;
        float* su  = (float*)(ws + n * 8);
        float* svx = su + n * 8;
        const int ge = ((n_edges + 1) / 2 + B - 1) / B;
        node_table_fb_kernel<false><<<gu, B, 0, stream>>>(x, a, hat_t, su, svx, nd, n_units);
        edge_sum_kernel<false><<<ge, B, 0, stream>>>(src, dst, et, su, svx, hat_t, nd, n_edges);
        finalize_kernel<<<gu, B, 0, stream>>>(nd, (float*)d_out, n_units);
    }
}